// Round 4
// baseline (9932.295 us; speedup 1.0000x reference)
//
#include <hip/hip_runtime.h>
#include <hip/hip_bf16.h>

// GraphEncoder: pre-Linear(3->32)+tanh -> GATConv(32->32, skeleton) -> LSTM(768->768, L=256)
// Inputs/outputs fp32 (proven R1->R3). Compute: bf16 MFMA operands, fp32 accum/state.
//
// Pipeline:
//   convert:   W_ih/W_hh fp32 -> bf16 canonical; small weights -> smallC fp32
//   gat_pre:   src -> Xb bf16 [32768][768]
//   gates_in:  G_in[32768][3072] = X @ W_ih^T + b_ih + b_hh  (one parallel GEMM)
//   persist:   all 256 LSTM steps in ONE kernel, 96 WGs, grid barrier per step,
//              c in registers, h ping-pong bf16 in ws, Whh L2-hot.
// Fallback: if ws_size too small for G_in, use the round-3 per-step path (known pass).
//
// ws layout (bytes):
//   0          Xb      bf16  50331648
//   50331648   WihC    bf16   4718592
//   55050240   WhhC    bf16   4718592
//   59768832   cs      fp32    393216   (legacy path only)
//   60162048   h0      bf16    196608
//   60358656   h1      bf16    196608
//   60555264   smallC  fp32     32768
//   60588032   bar     int       8192
//   60596224   G_in    fp32 402653184 | bf16 201326592

#define NB 128
#define LSEQ 256
#define LH 768
#define BGR 32768
#define NWG 96

typedef __attribute__((ext_vector_type(8))) short short8;
typedef __attribute__((ext_vector_type(4))) float floatx4;

// ---------------- Canonicalize weights (inputs are fp32) ----------------
// smallC: W_pre@0(96) b_pre@96(32) W_gat@128(1024) att_src@1152(32)
//         att_dst@1184(32) b_gat@1216(32) b_ih@1248(3072) b_hh@4320(3072)
__global__ __launch_bounds__(256) void convert_kernel(
    const float* W_pre, const float* b_pre, const float* W_gat,
    const float* att_src, const float* att_dst, const float* b_gat,
    const float* W_ih, const float* W_hh, const float* b_ih, const float* b_hh,
    __hip_bfloat16* __restrict__ WihC, __hip_bfloat16* __restrict__ WhhC,
    float* __restrict__ smallC)
{
    long i = (long)blockIdx.x * 256 + threadIdx.x;
    if (i < 2359296) { WihC[i] = __float2bfloat16(W_ih[i]); return; }
    i -= 2359296;
    if (i < 2359296) { WhhC[i] = __float2bfloat16(W_hh[i]); return; }
    i -= 2359296;
    if (i < 96)   { smallC[0 + i]    = W_pre[i];   return; }  i -= 96;
    if (i < 32)   { smallC[96 + i]   = b_pre[i];   return; }  i -= 32;
    if (i < 1024) { smallC[128 + i]  = W_gat[i];   return; }  i -= 1024;
    if (i < 32)   { smallC[1152 + i] = att_src[i]; return; }  i -= 32;
    if (i < 32)   { smallC[1184 + i] = att_dst[i]; return; }  i -= 32;
    if (i < 32)   { smallC[1216 + i] = b_gat[i];   return; }  i -= 32;
    if (i < 3072) { smallC[1248 + i] = b_ih[i];    return; }  i -= 3072;
    if (i < 3072) { smallC[4320 + i] = b_hh[i];    return; }
}

// ---------------- Kernel A: pre + GAT -> Xb (bf16) ----------------
__global__ __launch_bounds__(256) void gat_pre_kernel(
    const float* __restrict__ src,           // [32768][72]
    const float* __restrict__ smallC,
    __hip_bfloat16* __restrict__ Xb)         // [32768][768]
{
    __shared__ float wpre[96];
    __shared__ float bpre[32];
    __shared__ float wgat[1024];
    __shared__ float asrc[32];
    __shared__ float adst[32];
    __shared__ float bgat[32];
    __shared__ float xl[8][72];
    __shared__ float hl[8][24][32];
    __shared__ float xpl[8][24][32];
    __shared__ float asl[8][24];
    __shared__ float adl[8][24];

    const int tid = threadIdx.x;
    for (int i = tid; i < 96; i += 256)   wpre[i] = smallC[i];
    for (int i = tid; i < 1024; i += 256) wgat[i] = smallC[128 + i];
    if (tid < 32) {
        bpre[tid] = smallC[96 + tid];
        asrc[tid] = smallC[1152 + tid];
        adst[tid] = smallC[1184 + tid];
        bgat[tid] = smallC[1216 + tid];
    }

    const int g = tid >> 5;
    const int k = tid & 31;
    const long gb = (long)blockIdx.x * 8 + g;   // graph id = n*256 + t

    for (int i = k; i < 72; i += 32)
        xl[g][i] = src[gb * 72 + i];
    __syncthreads();

    #pragma unroll
    for (int j = 0; j < 24; ++j) {
        float v = xl[g][j*3+0] * wpre[0*32+k]
                + xl[g][j*3+1] * wpre[1*32+k]
                + xl[g][j*3+2] * wpre[2*32+k] + bpre[k];
        hl[g][j][k] = tanhf(v);
    }
    __syncthreads();

    #pragma unroll
    for (int j = 0; j < 24; ++j) {
        float v = 0.f;
        #pragma unroll
        for (int m = 0; m < 32; ++m) v += hl[g][j][m] * wgat[m*32 + k];
        xpl[g][j][k] = v;
    }
    __syncthreads();

    if (k < 24) {
        float vs = 0.f, vd = 0.f;
        #pragma unroll
        for (int m = 0; m < 32; ++m) {
            float x = xpl[g][k][m];
            vs += x * asrc[m];
            vd += x * adst[m];
        }
        asl[g][k] = vs;
        adl[g][k] = vd;
    }
    __syncthreads();

    const int par[24] = {-1,0,0,0,1,2,3,4,5,6,7,8,9,9,9,12,13,14,16,17,18,19,20,21};
    #pragma unroll
    for (int j = 0; j < 24; ++j) {
        int p = par[j];
        float o;
        if (p < 0) {
            o = xpl[g][j][k] + bgat[k];
        } else {
            float es = adl[g][j] + asl[g][j];
            float ep = adl[g][j] + asl[g][p];
            es = es > 0.f ? es : 0.2f * es;
            ep = ep > 0.f ? ep : 0.2f * ep;
            float mx = fmaxf(es, ep);
            float wse = expf(es - mx), wpe = expf(ep - mx);
            float inv = 1.f / (wse + wpe);
            o = (wse * xpl[g][j][k] + wpe * xpl[g][p][k]) * inv + bgat[k];
        }
        Xb[gb * 768 + j * 32 + k] = __float2bfloat16(o);
    }
}

// ---------------- Input-side gates GEMM: G_in = X @ W_ih^T + (b_ih + b_hh) ----------------
// grid (96, 256): blockIdx.x = col-WG (32 gate cols: 8 units x 4 gates), blockIdx.y = t.
__global__ __launch_bounds__(256) void gates_in_kernel(
    const __hip_bfloat16* __restrict__ Xb,    // [32768][768]
    const __hip_bfloat16* __restrict__ Wih,   // [3072][768]
    const float* __restrict__ smallC,
    float* __restrict__ Gf,                   // fp32 G_in (if ginf)
    __hip_bfloat16* __restrict__ Gb,          // bf16 G_in (else)
    int ginf)
{
    const int tid = threadIdx.x;
    const int t = blockIdx.y;
    const int w = tid >> 6;
    const int L = tid & 63;
    const int rh = w >> 1;
    const int ct = w & 1;
    const int q = L >> 4;
    const int col16 = L & 15;
    const int c_local = 16 * ct + col16;
    const int gate = c_local >> 3;
    const int uu = c_local & 7;
    const int u = 8 * blockIdx.x + uu;
    const int wrow = 768 * gate + u;

    const short8* bp = (const short8*)(Wih + (long)wrow * 768 + q * 8);
    const short8* ap[4];
    #pragma unroll
    for (int rt = 0; rt < 4; ++rt) {
        int m = 64 * rh + 16 * rt + col16;
        ap[rt] = (const short8*)(Xb + ((long)m * LSEQ + t) * 768 + q * 8);
    }

    floatx4 acc[4] = {};
    for (int kk = 0; kk < 768; kk += 32) {
        short8 bv = bp[kk >> 3];
        #pragma unroll
        for (int rt = 0; rt < 4; ++rt) {
            short8 av = ap[rt][kk >> 3];
            acc[rt] = __builtin_amdgcn_mfma_f32_16x16x32_bf16(av, bv, acc[rt], 0, 0, 0);
        }
    }

    const float bias = smallC[1248 + wrow] + smallC[4320 + wrow];
    #pragma unroll
    for (int rt = 0; rt < 4; ++rt) {
        #pragma unroll
        for (int r = 0; r < 4; ++r) {
            int m = 64 * rh + 16 * rt + q * 4 + r;
            size_t idx = ((size_t)m * LSEQ + t) * 3072 + wrow;
            float v = acc[rt][r] + bias;
            if (ginf) Gf[idx] = v;
            else      Gb[idx] = __float2bfloat16(v);
        }
    }
}

// ---------------- Persistent LSTM: all 256 steps, one launch ----------------
// 96 WGs x 256 threads, all co-resident. Grid barrier per step via cnt[t]+epoch.
__global__ __launch_bounds__(256) void lstm_persist_kernel(
    const void* __restrict__ Gin,             // fp32 or bf16 per ginf
    const __hip_bfloat16* __restrict__ Whh,   // [3072][768]
    __hip_bfloat16* __restrict__ h0,          // ping-pong h (h0 zeroed = h(-1))
    __hip_bfloat16* __restrict__ h1,
    float* __restrict__ out,                  // fp32 [128][256][768] + h_n + c_n
    int* __restrict__ bar,                    // cnt[256], epoch at [256]
    int ginf)
{
    __shared__ float gl[128 * 33];

    const int tid = threadIdx.x;
    const int w = tid >> 6;
    const int L = tid & 63;
    const int rh = w >> 1;
    const int ct = w & 1;
    const int q = L >> 4;
    const int col16 = L & 15;
    const int c_local = 16 * ct + col16;
    const int gate = c_local >> 3;
    const int uu = c_local & 7;
    const int u = 8 * blockIdx.x + uu;
    const int wrow = 768 * gate + u;

    const short8* bp_h = (const short8*)(Whh + (long)wrow * 768 + q * 8);
    const int arow[4] = { 64*rh + 16*0 + col16, 64*rh + 16*1 + col16,
                          64*rh + 16*2 + col16, 64*rh + 16*3 + col16 };

    // per-thread cell state: item loop items {tid, tid+256, tid+512, tid+768}
    float c_reg[4] = {0.f, 0.f, 0.f, 0.f};
    const int im_m[4]  = { (tid >> 3), 32 + (tid >> 3), 64 + (tid >> 3), 96 + (tid >> 3) };
    const int im_u2l   = tid & 7;
    const int im_u2    = 8 * blockIdx.x + im_u2l;

    const float* Gf = (const float*)Gin;
    const __hip_bfloat16* Gb = (const __hip_bfloat16*)Gin;
    int* cnt = bar;
    int* epoch = bar + 256;

    for (int t = 0; t < LSEQ; ++t) {
        const __hip_bfloat16* hr = (t & 1) ? h1 : h0;
        __hip_bfloat16*       hw = (t & 1) ? h0 : h1;

        floatx4 acc[4] = {};
        for (int kk = 0; kk < 768; kk += 32) {
            short8 bv = bp_h[kk >> 3];
            #pragma unroll
            for (int rt = 0; rt < 4; ++rt) {
                short8 av = *(const short8*)(hr + (long)arow[rt] * 768 + q * 8 + kk);
                acc[rt] = __builtin_amdgcn_mfma_f32_16x16x32_bf16(av, bv, acc[rt], 0, 0, 0);
            }
        }

        #pragma unroll
        for (int rt = 0; rt < 4; ++rt) {
            #pragma unroll
            for (int r = 0; r < 4; ++r) {
                int m = 64 * rh + 16 * rt + q * 4 + r;
                gl[m * 33 + c_local] = acc[rt][r];
            }
        }
        __syncthreads();

        #pragma unroll
        for (int it = 0; it < 4; ++it) {
            const int m = im_m[it];
            const size_t gbase = ((size_t)m * LSEQ + t) * 3072;
            float ig, fg, gg, og;
            if (ginf) {
                ig = Gf[gbase + 768*0 + im_u2];
                fg = Gf[gbase + 768*1 + im_u2];
                gg = Gf[gbase + 768*2 + im_u2];
                og = Gf[gbase + 768*3 + im_u2];
            } else {
                ig = __bfloat162float(Gb[gbase + 768*0 + im_u2]);
                fg = __bfloat162float(Gb[gbase + 768*1 + im_u2]);
                gg = __bfloat162float(Gb[gbase + 768*2 + im_u2]);
                og = __bfloat162float(Gb[gbase + 768*3 + im_u2]);
            }
            ig += gl[m * 33 + 0  + im_u2l];
            fg += gl[m * 33 + 8  + im_u2l];
            gg += gl[m * 33 + 16 + im_u2l];
            og += gl[m * 33 + 24 + im_u2l];

            float si = 1.f / (1.f + expf(-ig));
            float sf = 1.f / (1.f + expf(-fg));
            float so = 1.f / (1.f + expf(-og));
            float cn = sf * c_reg[it] + si * tanhf(gg);
            float h  = so * tanhf(cn);
            c_reg[it] = cn;

            const int ci = m * LH + im_u2;
            hw[ci] = __float2bfloat16(h);
            out[((long)m * LSEQ + t) * LH + im_u2] = h;
            if (t == LSEQ - 1) {
                const long base = (long)NB * LSEQ * LH;
                out[base + ci] = h;
                out[base + NB * LH + ci] = cn;
            }
        }

        if (t < LSEQ - 1) {
            __syncthreads();                 // gl reuse + all hw writes issued
            if (tid == 0) {
                __threadfence();             // release h(t) device-wide
                int prev = __hip_atomic_fetch_add(&cnt[t], 1, __ATOMIC_ACQ_REL,
                                                  __HIP_MEMORY_SCOPE_AGENT);
                if (prev == NWG - 1) {
                    __hip_atomic_store(epoch, t + 1, __ATOMIC_RELEASE,
                                       __HIP_MEMORY_SCOPE_AGENT);
                } else {
                    while (__hip_atomic_load(epoch, __ATOMIC_ACQUIRE,
                                             __HIP_MEMORY_SCOPE_AGENT) < t + 1) {
                        __builtin_amdgcn_s_sleep(2);
                    }
                }
                __threadfence();             // acquire: invalidate L1 for whole CU
            }
            __syncthreads();
        }
    }
}

// ---------------- Legacy round-3 per-step path (ws fallback) ----------------
__global__ __launch_bounds__(256) void lstm_step_kernel(
    const __hip_bfloat16* __restrict__ Xb,
    const __hip_bfloat16* __restrict__ Wih,
    const __hip_bfloat16* __restrict__ Whh,
    const float* __restrict__ smallC,
    float* __restrict__ cst,
    const __hip_bfloat16* __restrict__ hr,
    __hip_bfloat16* __restrict__ hw,
    float* __restrict__ out,
    int t)
{
    __shared__ float gl[128 * 33];
    const int tid = threadIdx.x;
    const int w = tid >> 6;
    const int L = tid & 63;
    const int rh = w >> 1;
    const int ct = w & 1;
    const int q = L >> 4;
    const int col16 = L & 15;
    const int c_local = 16 * ct + col16;
    const int gate = c_local >> 3;
    const int uu = c_local & 7;
    const int u = 8 * blockIdx.x + uu;
    const int wrow = 768 * gate + u;

    const short8* bp_i = (const short8*)(Wih + (long)wrow * 768 + q * 8);
    const short8* bp_h = (const short8*)(Whh + (long)wrow * 768 + q * 8);
    const short8* ap_x[4];
    const short8* ap_h[4];
    #pragma unroll
    for (int rt = 0; rt < 4; ++rt) {
        int m = 64 * rh + 16 * rt + col16;
        ap_x[rt] = (const short8*)(Xb + ((long)m * LSEQ + t) * 768 + q * 8);
        ap_h[rt] = (const short8*)(hr + (long)m * 768 + q * 8);
    }
    floatx4 acc[4] = {};
    for (int kk = 0; kk < 768; kk += 32) {
        short8 bv = bp_i[kk >> 3];
        #pragma unroll
        for (int rt = 0; rt < 4; ++rt)
            acc[rt] = __builtin_amdgcn_mfma_f32_16x16x32_bf16(ap_x[rt][kk >> 3], bv, acc[rt], 0, 0, 0);
    }
    for (int kk = 0; kk < 768; kk += 32) {
        short8 bv = bp_h[kk >> 3];
        #pragma unroll
        for (int rt = 0; rt < 4; ++rt)
            acc[rt] = __builtin_amdgcn_mfma_f32_16x16x32_bf16(ap_h[rt][kk >> 3], bv, acc[rt], 0, 0, 0);
    }
    float bias = smallC[1248 + wrow] + smallC[4320 + wrow];
    #pragma unroll
    for (int rt = 0; rt < 4; ++rt)
        #pragma unroll
        for (int r = 0; r < 4; ++r) {
            int m = 64 * rh + 16 * rt + q * 4 + r;
            gl[m * 33 + c_local] = acc[rt][r] + bias;
        }
    __syncthreads();
    for (int item = tid; item < 1024; item += 256) {
        int m = item >> 3;
        int u2l = item & 7;
        float ig = gl[m * 33 + 0  + u2l];
        float fg = gl[m * 33 + 8  + u2l];
        float gg = gl[m * 33 + 16 + u2l];
        float og = gl[m * 33 + 24 + u2l];
        int u2 = 8 * blockIdx.x + u2l;
        int ci = m * 768 + u2;
        float co = cst[ci];
        float si = 1.f / (1.f + expf(-ig));
        float sf = 1.f / (1.f + expf(-fg));
        float so = 1.f / (1.f + expf(-og));
        float cn = sf * co + si * tanhf(gg);
        float h = so * tanhf(cn);
        cst[ci] = cn;
        hw[ci] = __float2bfloat16(h);
        out[((long)m * LSEQ + t) * 768 + u2] = h;
    }
}

__global__ __launch_bounds__(256) void finalize_kernel(
    const __hip_bfloat16* __restrict__ hfin,
    const float* __restrict__ cst,
    float* __restrict__ out)
{
    int i = blockIdx.x * 256 + threadIdx.x;
    const long base = (long)NB * LSEQ * LH;
    out[base + i] = __bfloat162float(hfin[i]);
    out[base + NB * LH + i] = cst[i];
}

extern "C" void kernel_launch(void* const* d_in, const int* in_sizes, int n_in,
                              void* d_out, int out_size, void* d_ws, size_t ws_size,
                              hipStream_t stream) {
    const float* src     = (const float*)d_in[0];
    const float* W_pre   = (const float*)d_in[1];
    const float* b_pre   = (const float*)d_in[2];
    const float* W_gat   = (const float*)d_in[3];
    const float* att_src = (const float*)d_in[4];
    const float* att_dst = (const float*)d_in[5];
    const float* b_gat   = (const float*)d_in[6];
    const float* W_ih    = (const float*)d_in[7];
    const float* W_hh    = (const float*)d_in[8];
    const float* b_ih    = (const float*)d_in[9];
    const float* b_hh    = (const float*)d_in[10];

    float* out = (float*)d_out;
    char* ws = (char*)d_ws;

    __hip_bfloat16* Xb     = (__hip_bfloat16*)(ws);
    __hip_bfloat16* WihC   = (__hip_bfloat16*)(ws + 50331648);
    __hip_bfloat16* WhhC   = (__hip_bfloat16*)(ws + 55050240);
    float*          cs     = (float*)         (ws + 59768832);
    __hip_bfloat16* h0     = (__hip_bfloat16*)(ws + 60162048);
    __hip_bfloat16* h1     = (__hip_bfloat16*)(ws + 60358656);
    float*          smallC = (float*)         (ws + 60555264);
    int*            bar    = (int*)           (ws + 60588032);
    void*           Gin    = (void*)          (ws + 60596224);

    const size_t base_need = 60596224;
    const size_t need_f32  = base_need + (size_t)BGR * 3072 * 4;   // 463 MB
    const size_t need_b16  = base_need + (size_t)BGR * 3072 * 2;   // 262 MB
    const int use_persist  = (ws_size >= need_b16);
    const int ginf         = (ws_size >= need_f32);

    hipMemsetAsync(h0, 0, NB * LH * sizeof(__hip_bfloat16), stream);

    const long conv_total = 2359296L * 2 + 7392;
    convert_kernel<<<(int)((conv_total + 255) / 256), 256, 0, stream>>>(
        W_pre, b_pre, W_gat, att_src, att_dst, b_gat,
        W_ih, W_hh, b_ih, b_hh, WihC, WhhC, smallC);

    gat_pre_kernel<<<BGR / 8, 256, 0, stream>>>(src, smallC, Xb);

    if (use_persist) {
        hipMemsetAsync(bar, 0, 8192, stream);
        dim3 ggrid(NWG, LSEQ);
        gates_in_kernel<<<ggrid, 256, 0, stream>>>(Xb, WihC, smallC,
                                                   (float*)Gin, (__hip_bfloat16*)Gin, ginf);
        lstm_persist_kernel<<<NWG, 256, 0, stream>>>(Gin, WhhC, h0, h1, out, bar, ginf);
    } else {
        hipMemsetAsync(cs, 0, NB * LH * sizeof(float), stream);
        __hip_bfloat16* hp[2] = {h0, h1};
        for (int t = 0; t < LSEQ; ++t) {
            lstm_step_kernel<<<NWG, 256, 0, stream>>>(Xb, WihC, WhhC, smallC,
                                                      cs, hp[t & 1], hp[(t + 1) & 1],
                                                      out, t);
        }
        finalize_kernel<<<NB * LH / 256, 256, 0, stream>>>(h0, cs, out);
    }
}

// Round 5
// 3077.216 us; speedup vs baseline: 3.2277x; 3.2277x over previous
//
#include <hip/hip_runtime.h>
#include <hip/hip_bf16.h>

// GraphEncoder: pre-Linear(3->32)+tanh -> GATConv(32->32, skeleton) -> LSTM(768->768, L=256)
// Inputs/outputs fp32 (proven R1->R3). Compute: bf16 MFMA operands, fp32 accum/state.
//
// d_in: src, W_pre, b_pre, W_gat, att_src, att_dst, b_gat, W_ih, W_hh, b_ih, b_hh
// d_out (fp32): [output 128*256*768][h_n 128*768][c_n 128*768]
//
// ws layout (bytes):
//   0          Xb      bf16  50331648
//   50331648   WihC    bf16   4718592
//   55050240   WhhC    bf16   4718592
//   59768832   cs      fp32    393216   (legacy path only)
//   60162048   h0      bf16    196608
//   60358656   h1      bf16    196608
//   60555264   smallC  fp32     32768
//   60588032   bar     int       8192   (group counters [t*8+g], epoch at [2040])
//   60596224   G       fp32 402653184 | bf16 201326592   (layout [t][128][3072])

#define NB 128
#define LSEQ 256
#define LH 768
#define BGR 32768
#define NWG 96     // legacy path
#define PWG 192    // persistent path: 96 col-groups x 2 row-groups

typedef __attribute__((ext_vector_type(8))) short short8;
typedef __attribute__((ext_vector_type(4))) float floatx4;
typedef __attribute__((ext_vector_type(4))) unsigned int uint4v;

union frag16 { uint4v u; short8 s; };
union bfbits { __hip_bfloat16 h; unsigned short s; };

__device__ __forceinline__ float bf16bits_to_f(unsigned short s) {
    unsigned u = ((unsigned)s) << 16;
    float f;
    __builtin_memcpy(&f, &u, 4);
    return f;
}

// 8 MALL-coherent 16B loads at base + {0..448}
__device__ __forceinline__ void issue8(uint4v* b, const char* base) {
    asm volatile("global_load_dwordx4 %0, %1, off sc0 sc1"            : "=v"(b[0]) : "v"(base));
    asm volatile("global_load_dwordx4 %0, %1, off offset:64 sc0 sc1"  : "=v"(b[1]) : "v"(base));
    asm volatile("global_load_dwordx4 %0, %1, off offset:128 sc0 sc1" : "=v"(b[2]) : "v"(base));
    asm volatile("global_load_dwordx4 %0, %1, off offset:192 sc0 sc1" : "=v"(b[3]) : "v"(base));
    asm volatile("global_load_dwordx4 %0, %1, off offset:256 sc0 sc1" : "=v"(b[4]) : "v"(base));
    asm volatile("global_load_dwordx4 %0, %1, off offset:320 sc0 sc1" : "=v"(b[5]) : "v"(base));
    asm volatile("global_load_dwordx4 %0, %1, off offset:384 sc0 sc1" : "=v"(b[6]) : "v"(base));
    asm volatile("global_load_dwordx4 %0, %1, off offset:448 sc0 sc1" : "=v"(b[7]) : "v"(base));
}
// waitcnt with register ties so the compiler cannot hoist consumers above it
__device__ __forceinline__ void wait8_touch(uint4v* b) {
    asm volatile("s_waitcnt vmcnt(8)"
        : "+v"(b[0]), "+v"(b[1]), "+v"(b[2]), "+v"(b[3]),
          "+v"(b[4]), "+v"(b[5]), "+v"(b[6]), "+v"(b[7]) :: "memory");
}
__device__ __forceinline__ void wait0_touch(uint4v* b) {
    asm volatile("s_waitcnt vmcnt(0)"
        : "+v"(b[0]), "+v"(b[1]), "+v"(b[2]), "+v"(b[3]),
          "+v"(b[4]), "+v"(b[5]), "+v"(b[6]), "+v"(b[7]) :: "memory");
}

// ---------------- Canonicalize weights (fp32 inputs) ----------------
// smallC: W_pre@0(96) b_pre@96(32) W_gat@128(1024) att_src@1152(32)
//         att_dst@1184(32) b_gat@1216(32) b_ih@1248(3072) b_hh@4320(3072)
__global__ __launch_bounds__(256) void convert_kernel(
    const float* W_pre, const float* b_pre, const float* W_gat,
    const float* att_src, const float* att_dst, const float* b_gat,
    const float* W_ih, const float* W_hh, const float* b_ih, const float* b_hh,
    __hip_bfloat16* __restrict__ WihC, __hip_bfloat16* __restrict__ WhhC,
    float* __restrict__ smallC)
{
    long i = (long)blockIdx.x * 256 + threadIdx.x;
    if (i < 2359296) { WihC[i] = __float2bfloat16(W_ih[i]); return; }
    i -= 2359296;
    if (i < 2359296) { WhhC[i] = __float2bfloat16(W_hh[i]); return; }
    i -= 2359296;
    if (i < 96)   { smallC[0 + i]    = W_pre[i];   return; }  i -= 96;
    if (i < 32)   { smallC[96 + i]   = b_pre[i];   return; }  i -= 32;
    if (i < 1024) { smallC[128 + i]  = W_gat[i];   return; }  i -= 1024;
    if (i < 32)   { smallC[1152 + i] = att_src[i]; return; }  i -= 32;
    if (i < 32)   { smallC[1184 + i] = att_dst[i]; return; }  i -= 32;
    if (i < 32)   { smallC[1216 + i] = b_gat[i];   return; }  i -= 32;
    if (i < 3072) { smallC[1248 + i] = b_ih[i];    return; }  i -= 3072;
    if (i < 3072) { smallC[4320 + i] = b_hh[i];    return; }
}

// ---------------- Kernel A: pre + GAT -> Xb (bf16) ----------------
__global__ __launch_bounds__(256) void gat_pre_kernel(
    const float* __restrict__ src,           // [32768][72]
    const float* __restrict__ smallC,
    __hip_bfloat16* __restrict__ Xb)         // [32768][768]
{
    __shared__ float wpre[96];
    __shared__ float bpre[32];
    __shared__ float wgat[1024];
    __shared__ float asrc[32];
    __shared__ float adst[32];
    __shared__ float bgat[32];
    __shared__ float xl[8][72];
    __shared__ float hl[8][24][32];
    __shared__ float xpl[8][24][32];
    __shared__ float asl[8][24];
    __shared__ float adl[8][24];

    const int tid = threadIdx.x;
    for (int i = tid; i < 96; i += 256)   wpre[i] = smallC[i];
    for (int i = tid; i < 1024; i += 256) wgat[i] = smallC[128 + i];
    if (tid < 32) {
        bpre[tid] = smallC[96 + tid];
        asrc[tid] = smallC[1152 + tid];
        adst[tid] = smallC[1184 + tid];
        bgat[tid] = smallC[1216 + tid];
    }

    const int g = tid >> 5;
    const int k = tid & 31;
    const long gb = (long)blockIdx.x * 8 + g;   // graph id = n*256 + t

    for (int i = k; i < 72; i += 32)
        xl[g][i] = src[gb * 72 + i];
    __syncthreads();

    #pragma unroll
    for (int j = 0; j < 24; ++j) {
        float v = xl[g][j*3+0] * wpre[0*32+k]
                + xl[g][j*3+1] * wpre[1*32+k]
                + xl[g][j*3+2] * wpre[2*32+k] + bpre[k];
        hl[g][j][k] = tanhf(v);
    }
    __syncthreads();

    #pragma unroll
    for (int j = 0; j < 24; ++j) {
        float v = 0.f;
        #pragma unroll
        for (int m = 0; m < 32; ++m) v += hl[g][j][m] * wgat[m*32 + k];
        xpl[g][j][k] = v;
    }
    __syncthreads();

    if (k < 24) {
        float vs = 0.f, vd = 0.f;
        #pragma unroll
        for (int m = 0; m < 32; ++m) {
            float x = xpl[g][k][m];
            vs += x * asrc[m];
            vd += x * adst[m];
        }
        asl[g][k] = vs;
        adl[g][k] = vd;
    }
    __syncthreads();

    const int par[24] = {-1,0,0,0,1,2,3,4,5,6,7,8,9,9,9,12,13,14,16,17,18,19,20,21};
    #pragma unroll
    for (int j = 0; j < 24; ++j) {
        int p = par[j];
        float o;
        if (p < 0) {
            o = xpl[g][j][k] + bgat[k];
        } else {
            float es = adl[g][j] + asl[g][j];
            float ep = adl[g][j] + asl[g][p];
            es = es > 0.f ? es : 0.2f * es;
            ep = ep > 0.f ? ep : 0.2f * ep;
            float mx = fmaxf(es, ep);
            float wse = expf(es - mx), wpe = expf(ep - mx);
            float inv = 1.f / (wse + wpe);
            o = (wse * xpl[g][j][k] + wpe * xpl[g][p][k]) * inv + bgat[k];
        }
        Xb[gb * 768 + j * 32 + k] = __float2bfloat16(o);
    }
}

// ---------------- gates_in v2: G = X @ Wih^T + (b_ih+b_hh), 128x128 tiles ----------------
// grid (256, 24): bx = M-block (rows m*256+t of Xb), by = N-block (wrows).
// G layout [t][128][3072].
__global__ __launch_bounds__(256) void gates_in_kernel(
    const __hip_bfloat16* __restrict__ Xb,   // [32768][768]
    const __hip_bfloat16* __restrict__ Wih,  // [3072][768]
    const float* __restrict__ smallC,
    float* __restrict__ Gf, __hip_bfloat16* __restrict__ Gb, int ginf)
{
    const int tid = threadIdx.x;
    const int w = tid >> 6, L = tid & 63;
    const int rh2 = w >> 1, ch2 = w & 1;
    const int q = L >> 4, col16 = L & 15;
    const int R0 = blockIdx.x * 128;
    const int N0 = blockIdx.y * 128;

    const short8* ap[4];
    const short8* bp[4];
    #pragma unroll
    for (int i = 0; i < 4; ++i) {
        ap[i] = (const short8*)(Xb + (size_t)(R0 + 64*rh2 + 16*i + col16) * 768 + q*8);
        bp[i] = (const short8*)(Wih + (size_t)(N0 + 64*ch2 + 16*i + col16) * 768 + q*8);
    }

    floatx4 acc[4][4] = {};
    for (int kk = 0; kk < 24; ++kk) {
        short8 a[4], b[4];
        #pragma unroll
        for (int i = 0; i < 4; ++i) { a[i] = ap[i][kk*4]; b[i] = bp[i][kk*4]; }
        #pragma unroll
        for (int rt = 0; rt < 4; ++rt)
            #pragma unroll
            for (int bt = 0; bt < 4; ++bt)
                acc[rt][bt] = __builtin_amdgcn_mfma_f32_16x16x32_bf16(a[rt], b[bt], acc[rt][bt], 0, 0, 0);
    }

    #pragma unroll
    for (int bt = 0; bt < 4; ++bt) {
        int wrow = N0 + 64*ch2 + 16*bt + col16;
        float bias = smallC[1248 + wrow] + smallC[4320 + wrow];
        #pragma unroll
        for (int rt = 0; rt < 4; ++rt) {
            #pragma unroll
            for (int r = 0; r < 4; ++r) {
                int m_abs = R0 + 64*rh2 + 16*rt + q*4 + r;   // = m*256 + t
                int mm = m_abs >> 8, tt = m_abs & 255;
                size_t idx = ((size_t)tt * 128 + mm) * 3072 + wrow;
                float v = acc[rt][bt][r] + bias;
                if (ginf) Gf[idx] = v;
                else      Gb[idx] = __float2bfloat16(v);
            }
        }
    }
}

// ---------------- Persistent LSTM: all 256 steps in one launch ----------------
// 192 WGs: cg = bx%96 (units cg*8..+7, 32 gate cols), rg = bx/96 (rows rg*64..+63).
// Wave w = row quarter (16 rows). Whh slice in LDS (blocked, conflict-free).
// h via sc0/sc1 (MALL-coherent) -> no L2-flushing fences. Relaxed agent atomics barrier.
__global__ __launch_bounds__(256) void lstm_persist_kernel(
    const void* __restrict__ Gin,             // [t][128][3072] fp32 or bf16
    const __hip_bfloat16* __restrict__ Whh,   // [3072][768]
    __hip_bfloat16* __restrict__ h0g,         // ping-pong h (h0 zeroed)
    __hip_bfloat16* __restrict__ h1g,
    float* __restrict__ out,
    int* __restrict__ bar,
    int ginf)
{
    __shared__ short8 whhs[3072];             // [kk][c*4+q] 16B fragments, 48 KB
    __shared__ float gl[64 * 33];             // gate staging, 8448 B

    const int tid = threadIdx.x;
    const int w = tid >> 6;                   // row quarter: rows 16w..16w+15 (local)
    const int L = tid & 63;
    const int q = L >> 4;
    const int col16 = L & 15;
    const int cg = blockIdx.x % 96;
    const int rg = blockIdx.x / 96;

    // ---- stage Whh slice into LDS (once): whhs[f], f=(kk<<7)|(c<<2)|q ----
    for (int b = 0; b < 12; ++b) {
        int f = tid + 256 * b;
        int kk = f >> 7, c = (f >> 2) & 31, qq = f & 3;
        int wrow = 768 * (c >> 3) + cg * 8 + (c & 7);
        whhs[f] = *(const short8*)(Whh + (size_t)wrow * 768 + kk * 32 + qq * 8);
    }
    __syncthreads();

    // epilogue assignment: thread -> (row m_loc, unit pair u2b)
    const int m_loc = tid >> 2;               // 0..63
    const int u2b = (tid & 3) * 2;            // 0,2,4,6
    const int m_glob = rg * 64 + m_loc;
    float creg0 = 0.f, creg1 = 0.f;

    const float* Gf = (const float*)Gin;
    const __hip_bfloat16* Gb = (const __hip_bfloat16*)Gin;

    for (int t = 0; t < LSEQ; ++t) {
        const char* hr = (const char*)((t & 1) ? h1g : h0g);
        __hip_bfloat16* hw = (t & 1) ? h0g : h1g;

        // ---- G loads early (independent of h) ----
        const size_t grow = ((size_t)t * 128 + m_glob) * 3072 + cg * 8 + u2b;
        float gI0, gI1, gF0, gF1, gG0, gG1, gO0, gO1;
        if (ginf) {
            float2 vI = *(const float2*)(Gf + grow);
            float2 vF = *(const float2*)(Gf + grow + 768);
            float2 vG = *(const float2*)(Gf + grow + 1536);
            float2 vO = *(const float2*)(Gf + grow + 2304);
            gI0 = vI.x; gI1 = vI.y; gF0 = vF.x; gF1 = vF.y;
            gG0 = vG.x; gG1 = vG.y; gO0 = vO.x; gO1 = vO.y;
        } else {
            unsigned vi = *(const unsigned*)(Gb + grow);
            unsigned vf = *(const unsigned*)(Gb + grow + 768);
            unsigned vg = *(const unsigned*)(Gb + grow + 1536);
            unsigned vo = *(const unsigned*)(Gb + grow + 2304);
            gI0 = bf16bits_to_f(vi & 0xFFFF); gI1 = bf16bits_to_f(vi >> 16);
            gF0 = bf16bits_to_f(vf & 0xFFFF); gF1 = bf16bits_to_f(vf >> 16);
            gG0 = bf16bits_to_f(vg & 0xFFFF); gG1 = bf16bits_to_f(vg >> 16);
            gO0 = bf16bits_to_f(vo & 0xFFFF); gO1 = bf16bits_to_f(vo >> 16);
        }

        // ---- recurrent GEMM: A = h rows (16 per wave) from MALL, B = Whh from LDS ----
        floatx4 acc0 = {}, acc1 = {};
        uint4v bufA[8], bufB[8];
        const char* hbase = hr + (size_t)(((rg * 64 + 16 * w + col16) * 768) + q * 8) * 2;

        issue8(bufA, hbase);
        issue8(bufB, hbase + 512);

        wait8_touch(bufA);
        #pragma unroll
        for (int j = 0; j < 8; ++j) {
            frag16 fu; fu.u = bufA[j];
            short8 bv0 = whhs[j * 128 + (col16 * 4 + q)];
            short8 bv1 = whhs[j * 128 + ((16 + col16) * 4 + q)];
            acc0 = __builtin_amdgcn_mfma_f32_16x16x32_bf16(fu.s, bv0, acc0, 0, 0, 0);
            acc1 = __builtin_amdgcn_mfma_f32_16x16x32_bf16(fu.s, bv1, acc1, 0, 0, 0);
        }
        issue8(bufA, hbase + 1024);
        wait8_touch(bufB);
        #pragma unroll
        for (int j = 0; j < 8; ++j) {
            frag16 fu; fu.u = bufB[j];
            short8 bv0 = whhs[(8 + j) * 128 + (col16 * 4 + q)];
            short8 bv1 = whhs[(8 + j) * 128 + ((16 + col16) * 4 + q)];
            acc0 = __builtin_amdgcn_mfma_f32_16x16x32_bf16(fu.s, bv0, acc0, 0, 0, 0);
            acc1 = __builtin_amdgcn_mfma_f32_16x16x32_bf16(fu.s, bv1, acc1, 0, 0, 0);
        }
        wait0_touch(bufA);
        #pragma unroll
        for (int j = 0; j < 8; ++j) {
            frag16 fu; fu.u = bufA[j];
            short8 bv0 = whhs[(16 + j) * 128 + (col16 * 4 + q)];
            short8 bv1 = whhs[(16 + j) * 128 + ((16 + col16) * 4 + q)];
            acc0 = __builtin_amdgcn_mfma_f32_16x16x32_bf16(fu.s, bv0, acc0, 0, 0, 0);
            acc1 = __builtin_amdgcn_mfma_f32_16x16x32_bf16(fu.s, bv1, acc1, 0, 0, 0);
        }

        // ---- D -> gl: row = 16w + q*4 + r, cols col16 / 16+col16 ----
        #pragma unroll
        for (int r = 0; r < 4; ++r) {
            int mr = 16 * w + q * 4 + r;
            gl[mr * 33 + col16] = acc0[r];
            gl[mr * 33 + 16 + col16] = acc1[r];
        }
        __syncthreads();

        // ---- elementwise LSTM update (pair of units per thread) ----
        float ig0 = gI0 + gl[m_loc * 33 + 0  + u2b];
        float fg0 = gF0 + gl[m_loc * 33 + 8  + u2b];
        float gg0 = gG0 + gl[m_loc * 33 + 16 + u2b];
        float og0 = gO0 + gl[m_loc * 33 + 24 + u2b];
        float ig1 = gI1 + gl[m_loc * 33 + 0  + u2b + 1];
        float fg1 = gF1 + gl[m_loc * 33 + 8  + u2b + 1];
        float gg1 = gG1 + gl[m_loc * 33 + 16 + u2b + 1];
        float og1 = gO1 + gl[m_loc * 33 + 24 + u2b + 1];

        float si0 = 1.f / (1.f + expf(-ig0)), sf0 = 1.f / (1.f + expf(-fg0));
        float so0 = 1.f / (1.f + expf(-og0));
        float cn0 = sf0 * creg0 + si0 * tanhf(gg0);
        float hv0 = so0 * tanhf(cn0);
        creg0 = cn0;
        float si1 = 1.f / (1.f + expf(-ig1)), sf1 = 1.f / (1.f + expf(-fg1));
        float so1 = 1.f / (1.f + expf(-og1));
        float cn1 = sf1 * creg1 + si1 * tanhf(gg1);
        float hv1 = so1 * tanhf(cn1);
        creg1 = cn1;

        // h write: 2 bf16 packed, MALL-coherent
        bfbits b0, b1;
        b0.h = __float2bfloat16(hv0);
        b1.h = __float2bfloat16(hv1);
        unsigned hpack = (unsigned)b0.s | ((unsigned)b1.s << 16);
        char* ha = (char*)hw + (size_t)(m_glob * 768 + cg * 8 + u2b) * 2;
        asm volatile("global_store_dword %0, %1, off sc0 sc1" :: "v"(ha), "v"(hpack) : "memory");

        // out write (fp32)
        float2 ov; ov.x = hv0; ov.y = hv1;
        *(float2*)(out + ((size_t)m_glob * 256 + t) * 768 + cg * 8 + u2b) = ov;

        if (t == LSEQ - 1) {
            const size_t base = (size_t)NB * LSEQ * LH;
            const size_t ci = (size_t)m_glob * 768 + cg * 8 + u2b;
            float2 hv; hv.x = hv0; hv.y = hv1;
            float2 cv; cv.x = cn0; cv.y = cn1;
            *(float2*)(out + base + ci) = hv;
            *(float2*)(out + base + (size_t)NB * LH + ci) = cv;
        }

        // ---- grid barrier (two-level, relaxed agent atomics, no cache fences) ----
        if (t < LSEQ - 1) {
            asm volatile("s_waitcnt vmcnt(0)" ::: "memory");   // h at MALL
            __syncthreads();
            if (tid == 0) {
                int g = blockIdx.x & 7;
                int prev = __hip_atomic_fetch_add(&bar[t * 8 + g], 1,
                                                  __ATOMIC_RELAXED, __HIP_MEMORY_SCOPE_AGENT);
                bool rel = false;
                if ((prev & 255) == 23) {                      // 24th of this group
                    int pr = __hip_atomic_fetch_add(&bar[t * 8], 256,
                                                    __ATOMIC_RELAXED, __HIP_MEMORY_SCOPE_AGENT);
                    if ((pr >> 8) == 7) {                      // 8th group
                        __hip_atomic_store(&bar[2040], t + 1,
                                           __ATOMIC_RELAXED, __HIP_MEMORY_SCOPE_AGENT);
                        rel = true;
                    }
                }
                if (!rel) {
                    while (__hip_atomic_load(&bar[2040], __ATOMIC_RELAXED,
                                             __HIP_MEMORY_SCOPE_AGENT) < t + 1)
                        __builtin_amdgcn_s_sleep(8);
                }
            }
            __syncthreads();
        }
    }
}

// ---------------- Legacy round-3 per-step path (ws fallback, proven) ----------------
__global__ __launch_bounds__(256) void lstm_step_kernel(
    const __hip_bfloat16* __restrict__ Xb,
    const __hip_bfloat16* __restrict__ Wih,
    const __hip_bfloat16* __restrict__ Whh,
    const float* __restrict__ smallC,
    float* __restrict__ cst,
    const __hip_bfloat16* __restrict__ hr,
    __hip_bfloat16* __restrict__ hw,
    float* __restrict__ out,
    int t)
{
    __shared__ float gls[128 * 33];
    const int tid = threadIdx.x;
    const int w = tid >> 6;
    const int L = tid & 63;
    const int rh = w >> 1;
    const int ct = w & 1;
    const int q = L >> 4;
    const int col16 = L & 15;
    const int c_local = 16 * ct + col16;
    const int gate = c_local >> 3;
    const int uu = c_local & 7;
    const int u = 8 * blockIdx.x + uu;
    const int wrow = 768 * gate + u;

    const short8* bp_i = (const short8*)(Wih + (long)wrow * 768 + q * 8);
    const short8* bp_h = (const short8*)(Whh + (long)wrow * 768 + q * 8);
    const short8* ap_x[4];
    const short8* ap_h[4];
    #pragma unroll
    for (int rt = 0; rt < 4; ++rt) {
        int m = 64 * rh + 16 * rt + col16;
        ap_x[rt] = (const short8*)(Xb + ((long)m * LSEQ + t) * 768 + q * 8);
        ap_h[rt] = (const short8*)(hr + (long)m * 768 + q * 8);
    }
    floatx4 acc[4] = {};
    for (int kk = 0; kk < 768; kk += 32) {
        short8 bv = bp_i[kk >> 3];
        #pragma unroll
        for (int rt = 0; rt < 4; ++rt)
            acc[rt] = __builtin_amdgcn_mfma_f32_16x16x32_bf16(ap_x[rt][kk >> 3], bv, acc[rt], 0, 0, 0);
    }
    for (int kk = 0; kk < 768; kk += 32) {
        short8 bv = bp_h[kk >> 3];
        #pragma unroll
        for (int rt = 0; rt < 4; ++rt)
            acc[rt] = __builtin_amdgcn_mfma_f32_16x16x32_bf16(ap_h[rt][kk >> 3], bv, acc[rt], 0, 0, 0);
    }
    float bias = smallC[1248 + wrow] + smallC[4320 + wrow];
    #pragma unroll
    for (int rt = 0; rt < 4; ++rt)
        #pragma unroll
        for (int r = 0; r < 4; ++r) {
            int m = 64 * rh + 16 * rt + q * 4 + r;
            gls[m * 33 + c_local] = acc[rt][r] + bias;
        }
    __syncthreads();
    for (int item = tid; item < 1024; item += 256) {
        int m = item >> 3;
        int u2l = item & 7;
        float ig = gls[m * 33 + 0  + u2l];
        float fg = gls[m * 33 + 8  + u2l];
        float gg = gls[m * 33 + 16 + u2l];
        float og = gls[m * 33 + 24 + u2l];
        int u2 = 8 * blockIdx.x + u2l;
        int ci = m * 768 + u2;
        float co = cst[ci];
        float si = 1.f / (1.f + expf(-ig));
        float sf = 1.f / (1.f + expf(-fg));
        float so = 1.f / (1.f + expf(-og));
        float cn = sf * co + si * tanhf(gg);
        float h = so * tanhf(cn);
        cst[ci] = cn;
        hw[ci] = __float2bfloat16(h);
        out[((long)m * LSEQ + t) * 768 + u2] = h;
    }
}

__global__ __launch_bounds__(256) void finalize_kernel(
    const __hip_bfloat16* __restrict__ hfin,
    const float* __restrict__ cst,
    float* __restrict__ out)
{
    int i = blockIdx.x * 256 + threadIdx.x;
    const long base = (long)NB * LSEQ * LH;
    out[base + i] = __bfloat162float(hfin[i]);
    out[base + NB * LH + i] = cst[i];
}

extern "C" void kernel_launch(void* const* d_in, const int* in_sizes, int n_in,
                              void* d_out, int out_size, void* d_ws, size_t ws_size,
                              hipStream_t stream) {
    const float* src     = (const float*)d_in[0];
    const float* W_pre   = (const float*)d_in[1];
    const float* b_pre   = (const float*)d_in[2];
    const float* W_gat   = (const float*)d_in[3];
    const float* att_src = (const float*)d_in[4];
    const float* att_dst = (const float*)d_in[5];
    const float* b_gat   = (const float*)d_in[6];
    const float* W_ih    = (const float*)d_in[7];
    const float* W_hh    = (const float*)d_in[8];
    const float* b_ih    = (const float*)d_in[9];
    const float* b_hh    = (const float*)d_in[10];

    float* out = (float*)d_out;
    char* ws = (char*)d_ws;

    __hip_bfloat16* Xb     = (__hip_bfloat16*)(ws);
    __hip_bfloat16* WihC   = (__hip_bfloat16*)(ws + 50331648);
    __hip_bfloat16* WhhC   = (__hip_bfloat16*)(ws + 55050240);
    float*          cs     = (float*)         (ws + 59768832);
    __hip_bfloat16* h0     = (__hip_bfloat16*)(ws + 60162048);
    __hip_bfloat16* h1     = (__hip_bfloat16*)(ws + 60358656);
    float*          smallC = (float*)         (ws + 60555264);
    int*            bar    = (int*)           (ws + 60588032);
    void*           Gin    = (void*)          (ws + 60596224);

    const size_t base_need = 60596224;
    const size_t need_f32  = base_need + (size_t)BGR * 3072 * 4;   // ~463 MB
    const size_t need_b16  = base_need + (size_t)BGR * 3072 * 2;   // ~262 MB
    const int use_persist  = (ws_size >= need_b16);
    const int ginf         = (ws_size >= need_f32);

    hipMemsetAsync(h0, 0, NB * LH * sizeof(__hip_bfloat16), stream);

    const long conv_total = 2359296L * 2 + 7392;
    convert_kernel<<<(int)((conv_total + 255) / 256), 256, 0, stream>>>(
        W_pre, b_pre, W_gat, att_src, att_dst, b_gat,
        W_ih, W_hh, b_ih, b_hh, WihC, WhhC, smallC);

    gat_pre_kernel<<<BGR / 8, 256, 0, stream>>>(src, smallC, Xb);

    if (use_persist) {
        hipMemsetAsync(bar, 0, 8192, stream);
        dim3 ggrid(256, 24);
        gates_in_kernel<<<ggrid, 256, 0, stream>>>(Xb, WihC, smallC,
                                                   (float*)Gin, (__hip_bfloat16*)Gin, ginf);
        lstm_persist_kernel<<<PWG, 256, 0, stream>>>(Gin, WhhC, h0, h1, out, bar, ginf);
    } else {
        hipMemsetAsync(cs, 0, NB * LH * sizeof(float), stream);
        __hip_bfloat16* hp[2] = {h0, h1};
        for (int t = 0; t < LSEQ; ++t) {
            lstm_step_kernel<<<NWG, 256, 0, stream>>>(Xb, WihC, WhhC, smallC,
                                                      cs, hp[t & 1], hp[(t + 1) & 1],
                                                      out, t);
        }
        finalize_kernel<<<NB * LH / 256, 256, 0, stream>>>(h0, cs, out);
    }
}